// Round 1
// baseline (283.228 us; speedup 1.0000x reference)
//
#include <hip/hip_runtime.h>

constexpr int B      = 4;
constexpr int T      = 4096;
constexpr int C      = 64;      // input dim
constexpr int H      = 64;      // head dim
constexpr int TILE   = 32;      // rows per block
constexpr int HALO   = 2;       // window radius
constexpr int HR     = TILE + 2 * HALO;   // 36 halo rows
constexpr int LS     = 68;      // LDS row stride (floats): 16B-aligned, breaks pow2 banks
constexpr int NT     = 256;     // threads per block
constexpr int NTILES = T / TILE; // 128

// Compute dst[r][h] = sum_c sX[r+srcOff][c] * sW[c][h]  (i.e. X @ W^T, sW holds W transposed)
// 4 rows x 8 cols per thread; rows strided by nrt so lanes hit distinct LDS banks.
__device__ __forceinline__ void compute_mat(float (*__restrict__ dst)[LS],
                                            const float (*__restrict__ sXl)[LS],
                                            const float (*__restrict__ sWl)[LS],
                                            const int rows, const int srcOff,
                                            const int tid)
{
    const int nrt = rows >> 2;            // 8 (Q) or 9 (K/V)
    if (tid < nrt * 8) {
        const int rt = tid >> 3;
        const int h0 = (tid & 7) << 3;
        int r[4];
#pragma unroll
        for (int k = 0; k < 4; ++k) r[k] = rt + k * nrt + srcOff;

        float acc[4][8];
#pragma unroll
        for (int k = 0; k < 4; ++k)
#pragma unroll
            for (int j = 0; j < 8; ++j) acc[k][j] = 0.f;

        for (int c4 = 0; c4 < C; c4 += 4) {
            float xv[4][4];
#pragma unroll
            for (int k = 0; k < 4; ++k)
                *(float4*)&xv[k][0] = *(const float4*)&sXl[r[k]][c4];
#pragma unroll
            for (int cc = 0; cc < 4; ++cc) {
                const float4 wA = *(const float4*)&sWl[c4 + cc][h0];
                const float4 wB = *(const float4*)&sWl[c4 + cc][h0 + 4];
#pragma unroll
                for (int k = 0; k < 4; ++k) {
                    const float xs = xv[k][cc];
                    acc[k][0] = fmaf(xs, wA.x, acc[k][0]);
                    acc[k][1] = fmaf(xs, wA.y, acc[k][1]);
                    acc[k][2] = fmaf(xs, wA.z, acc[k][2]);
                    acc[k][3] = fmaf(xs, wA.w, acc[k][3]);
                    acc[k][4] = fmaf(xs, wB.x, acc[k][4]);
                    acc[k][5] = fmaf(xs, wB.y, acc[k][5]);
                    acc[k][6] = fmaf(xs, wB.z, acc[k][6]);
                    acc[k][7] = fmaf(xs, wB.w, acc[k][7]);
                }
            }
        }
#pragma unroll
        for (int k = 0; k < 4; ++k) {
            const int rr = r[k] - srcOff;
            *(float4*)&dst[rr][h0]     = make_float4(acc[k][0], acc[k][1], acc[k][2], acc[k][3]);
            *(float4*)&dst[rr][h0 + 4] = make_float4(acc[k][4], acc[k][5], acc[k][6], acc[k][7]);
        }
    }
}

__global__ __launch_bounds__(NT, 2)
void sparse_attn_fused(const float* __restrict__ x,
                       const float* __restrict__ Wq,
                       const float* __restrict__ Wk,
                       const float* __restrict__ Wv,
                       float* __restrict__ out)
{
    __shared__ float sX[HR][LS];      // x halo rows
    __shared__ float sW[C][LS];       // one W, transposed: sW[c][h] = W[h][c]
    __shared__ float sQ[TILE][LS];
    __shared__ float sK[HR][LS];
    __shared__ float sV[HR][LS];
    __shared__ float sS[TILE][8];     // scores, then probs (5 used per row)

    const int tid  = threadIdx.x;
    const int b    = blockIdx.x / NTILES;
    const int tile = blockIdx.x % NTILES;
    const int row0 = tile * TILE;
    const float* xb = x + (size_t)b * T * C;
    const size_t attnBase = (size_t)B * T * H;
    float* attnBlock = out + attnBase + ((size_t)b * T + row0) * T;

    // ---- phase 0: stage x halo, stage Wq^T, issue zero-fill of this block's attn rows ----
    for (int s = tid; s < HR * (C / 4); s += NT) {
        const int lr = s >> 4;
        const int c4 = (s & 15) << 2;
        const int gr = row0 + lr - HALO;
        float4 v = make_float4(0.f, 0.f, 0.f, 0.f);
        if (gr >= 0 && gr < T) v = *(const float4*)(xb + (size_t)gr * C + c4);
        *(float4*)&sX[lr][c4] = v;
    }
    for (int s = tid; s < C * H; s += NT) sW[s & 63][s >> 6] = Wq[s];
    {
        // 32 rows x 4096 cols of zeros. Band entries overwritten by softmax later;
        // ordering is guaranteed by the vmcnt(0) drain at each __syncthreads below.
        float4* dst = (float4*)attnBlock;
        const float4 z = make_float4(0.f, 0.f, 0.f, 0.f);
        for (int s = tid; s < TILE * (T / 4); s += NT) dst[s] = z;
    }
    __syncthreads();

    // ---- Q = X[tile] @ Wq^T ----
    compute_mat(sQ, sX, sW, TILE, HALO, tid);
    __syncthreads();

    for (int s = tid; s < C * H; s += NT) sW[s & 63][s >> 6] = Wk[s];
    __syncthreads();

    // ---- K = X[halo] @ Wk^T ----
    compute_mat(sK, sX, sW, HR, 0, tid);
    __syncthreads();

    // ---- scores (32 rows x 5 offsets); also stage Wv^T ----
    if (tid < TILE * 5) {
        const int i  = tid / 5;
        const int dj = tid % 5;
        const int jg = row0 + i - HALO + dj;   // global j within batch
        float sc = -__builtin_inff();
        if (jg >= 0 && jg < T) {
            float acc = 0.f;
#pragma unroll
            for (int h4 = 0; h4 < C; h4 += 4) {
                const float4 q = *(const float4*)&sQ[i][h4];
                const float4 k = *(const float4*)&sK[i + dj][h4];
                acc += q.x * k.x + q.y * k.y + q.z * k.z + q.w * k.w;
            }
            // scale = C^-0.5 = 0.125 ; triu(+1) bias inside band for j > i (dj > 2)
            sc = acc * 0.125f + (dj > 2 ? 1.0f : 0.0f);
        }
        sS[i][dj] = sc;
    }
    for (int s = tid; s < C * H; s += NT) sW[s & 63][s >> 6] = Wv[s];
    __syncthreads();

    // ---- softmax per row + write band attn entries ----
    if (tid < TILE) {
        const int i  = tid;
        const int ig = row0 + i;
        float sc[5];
        float m = -__builtin_inff();
#pragma unroll
        for (int d = 0; d < 5; ++d) { sc[d] = sS[i][d]; m = fmaxf(m, sc[d]); }
        float p[5];
        float sum = 0.f;
#pragma unroll
        for (int d = 0; d < 5; ++d) { p[d] = expf(sc[d] - m); sum += p[d]; }
        const float inv = 1.f / sum;
        float* rowp = out + attnBase + ((size_t)b * T + ig) * T;
#pragma unroll
        for (int d = 0; d < 5; ++d) {
            const float pv = p[d] * inv;   // exp(-inf)=0 for invalid -> prob 0
            sS[i][d] = pv;
            const int j = ig - HALO + d;
            if (j >= 0 && j < T) rowp[j] = pv;
        }
    }
    __syncthreads();

    // ---- V = X[halo] @ Wv^T ----
    compute_mat(sV, sX, sW, HR, 0, tid);
    __syncthreads();

    // ---- op = P @ V ----
    for (int s = tid; s < TILE * H; s += NT) {
        const int h = s & 63;
        const int r = s >> 6;
        float acc = 0.f;
#pragma unroll
        for (int d = 0; d < 5; ++d) acc = fmaf(sS[r][d], sV[r + d][h], acc);
        out[((size_t)b * T + row0 + r) * H + h] = acc;
    }
}

extern "C" void kernel_launch(void* const* d_in, const int* in_sizes, int n_in,
                              void* d_out, int out_size, void* d_ws, size_t ws_size,
                              hipStream_t stream) {
    (void)in_sizes; (void)n_in; (void)d_ws; (void)ws_size; (void)out_size;
    const float* x  = (const float*)d_in[0];
    const float* Wq = (const float*)d_in[1];
    const float* Wk = (const float*)d_in[2];
    const float* Wv = (const float*)d_in[3];
    float* out = (float*)d_out;
    sparse_attn_fused<<<dim3(B * NTILES), dim3(NT), 0, stream>>>(x, Wq, Wk, Wv, out);
}